// Round 7
// baseline (894.474 us; speedup 1.0000x reference)
//
#include <hip/hip_runtime.h>
#include <hip/hip_bf16.h>
#include <hip/hip_fp16.h>

constexpr int Nn = 100000;
constexpr int Ee = 1200000;
constexpr int Ll = 5;
constexpr int Gg = 128;
constexpr int PDim = 320; // L*D

typedef short short8 __attribute__((ext_vector_type(8)));
typedef float f32x4 __attribute__((ext_vector_type(4)));

union U4S8 { uint4 u; short8 s; };

__device__ inline float bfl(uint u) { return __uint_as_float(u << 16); }
__device__ inline ushort f2bf(float f) {
    const uint u = __float_as_uint(f);
    return (ushort)((u + 0x7fffu + ((u >> 16) & 1u)) >> 16);
}
__device__ inline uint pack2(float lo, float hi) {
    return (uint)f2bf(lo) | ((uint)f2bf(hi) << 16);
}
__device__ inline ushort f2h(float f) {
    const __half h = __float2half(f);
    return *(const ushort*)&h;
}
__device__ inline float h2f_lo(uint u) {
    const ushort s = (ushort)(u & 0xffffu);
    return __half2float(*(const __half*)&s);
}
__device__ inline float h2f_hi(uint u) {
    const ushort s = (ushort)(u >> 16);
    return __half2float(*(const __half*)&s);
}
// split x0,x1 into packed bf16 hi word + bf16 lo (residual) word
__device__ inline void split2(float x0, float x1, uint& hi, uint& lo) {
    const ushort h0 = f2bf(x0), h1 = f2bf(x1);
    hi = (uint)h0 | ((uint)h1 << 16);
    const float r0 = x0 - __uint_as_float((uint)h0 << 16);
    const float r1 = x1 - __uint_as_float((uint)h1 << 16);
    lo = pack2(r0, r1);
}

__device__ inline int lower_bound_i(const int* __restrict__ a, int n, int v)
{
    int lo = 0, hi = n;
    while (lo < hi) {
        const int m = (lo + hi) >> 1;
        if (a[m] < v) lo = m + 1; else hi = m;
    }
    return lo;
}

// ---------------------------------------------------------------------------
// init: sc = identity BN, stats=0, poolZ=0, per-graph node counts.
// ---------------------------------------------------------------------------
__global__ __launch_bounds__(256) void init_misc(
    const int* __restrict__ batch, float* __restrict__ sc,
    float* __restrict__ stats, float* __restrict__ poolZ,
    int* __restrict__ cnt)
{
    const int t = threadIdx.x;
    if (t < 64) { sc[t] = 1.f; sc[64 + t] = 0.f; }
    if (t < 128) {
        stats[t] = 0.f;
        const int lo = lower_bound_i(batch, Nn, t);
        const int hi = lower_bound_i(batch, Nn, t + 1);
        cnt[t] = hi - lo;
    }
    for (int i = t; i < Gg * 64; i += 256) poolZ[i] = 0.f;
}

// ---------------------------------------------------------------------------
// Weight conversion: Ws + 5x W2 -> bf16 TRANSPOSED hi/lo ([col][k]).
// Block m: 0=Ws, 1..5=W2[m-1].
// ---------------------------------------------------------------------------
__global__ __launch_bounds__(256) void conv_weights(
    const float* __restrict__ Ws, const float* __restrict__ W2,
    ushort* __restrict__ WThi, ushort* __restrict__ WTlo)
{
    const int m = blockIdx.x;
    const float* src = (m == 0) ? Ws : W2 + (size_t)(m - 1) * 4096;
    ushort* dh = WThi + (size_t)m * 4096;
    ushort* dl = WTlo + (size_t)m * 4096;
    const int t = threadIdx.x;
    const int col = t & 63;
    const int k0 = (t >> 6) * 16;
    #pragma unroll
    for (int i = 0; i < 16; i++) {
        const int k = k0 + i;
        const float w = src[k * 64 + col];
        const ushort h = f2bf(w);
        dh[col * 64 + k] = h;
        dl[col * 64 + k] = f2bf(w - __uint_as_float((uint)h << 16));
    }
}

// ---------------------------------------------------------------------------
// Per-layer prep (grid 49):
//  blocks 0..15 : WT1' = split(scale[k] * W1[k][c]) (transposed hi/lo)
//  block  16    : shiftW1[c] = sum_k shift[k] * W1[k][c]
//  blocks 17..48: pooled[layer-1] = scale*poolZ + cnt*shift (if layer>0);
//                 then zero poolZ for this layer's pool_z.
// ---------------------------------------------------------------------------
__global__ __launch_bounds__(256) void prep_layer(
    const float* __restrict__ W1, const float* __restrict__ sc,
    ushort* __restrict__ WT1hi, ushort* __restrict__ WT1lo,
    float* __restrict__ shiftW1, float* __restrict__ poolZ,
    const int* __restrict__ cnt, float* __restrict__ pooled, int layer)
{
    const int b = blockIdx.x;
    const int t = threadIdx.x;
    if (b < 16) {
        const int idx = b * 256 + t;      // == c*64 + k
        const int c = idx >> 6, k = idx & 63;
        const float w = sc[k] * W1[k * 64 + c];
        const ushort h = f2bf(w);
        WT1hi[idx] = h;
        WT1lo[idx] = f2bf(w - __uint_as_float((uint)h << 16));
    } else if (b == 16) {
        if (t < 64) {
            float s = 0.f;
            for (int k = 0; k < 64; k++) s += sc[64 + k] * W1[k * 64 + t];
            shiftW1[t] = s;
        }
    } else {
        const int idx = (b - 17) * 256 + t; // 0..8191
        const int g = idx >> 6, c = idx & 63;
        if (layer > 0)
            pooled[g * PDim + (layer - 1) * 64 + c] =
                sc[c] * poolZ[g * 64 + c] + (float)cnt[g] * sc[64 + c];
        poolZ[g * 64 + c] = 0.f;
    }
}

__global__ __launch_bounds__(256) void final_pool(
    const float* __restrict__ sc, const float* __restrict__ poolZ,
    const int* __restrict__ cnt, float* __restrict__ pooled)
{
    const int idx = blockIdx.x * 256 + threadIdx.x; // 8192
    const int g = idx >> 6, c = idx & 63;
    pooled[g * PDim + 4 * 64 + c] =
        sc[c] * poolZ[g * 64 + c] + (float)cnt[g] * sc[64 + c];
}

// ---------------------------------------------------------------------------
// Split-bf16 MFMA GEMM.
// AMODE 0: A = A1 (f32 rows).
// AMODE 2: A = A1[self] (f32) + sum_{nbr via CSR} Ash (fp16 shadow);
//          epilogue adds (1+deg[row])*shiftW1[col] (deferred-BN shift term).
// acc += Alo*Whi + Ahi*Wlo + Ahi*Whi (3 MFMA -> f32-grade).
// Block 256 = 4 waves; wave w owns rows blk*64+w*16..+16, all 64 cols.
// STATS: fused per-column sum/sumsq into stats. SHADOW: also write fp16 Y.
// ---------------------------------------------------------------------------
template<int AMODE, bool RELU, bool STATS, bool SHADOW>
__global__ __launch_bounds__(256) void gemm_mfma(
    const float* __restrict__ A1, const ushort* __restrict__ Ash,
    const int* __restrict__ rowptr, const int* __restrict__ colidx,
    const int* __restrict__ deg, const float* __restrict__ shiftW1,
    const ushort* __restrict__ WThi, const ushort* __restrict__ WTlo,
    const float* __restrict__ bias, float* __restrict__ Y,
    ushort* __restrict__ Ys, float* __restrict__ stats)
{
    const int t = threadIdx.x;
    const int w = t >> 6;
    const int l = t & 63;
    const int lr = l & 15;   // A-row / B-col within tile
    const int lk = l >> 4;   // k-group (8 elems each)

    // A fragments (NO early return: MFMA is wave-collective)
    const int arow = blockIdx.x * 64 + w * 16 + lr;
    short8 aHi[2], aLo[2];
    if (arow < Nn) {
        float v0[8], v1[8];
        {
            const float* p = A1 + (size_t)arow * 64 + lk * 8;
            const float4 a = *(const float4*)p;
            const float4 b = *(const float4*)(p + 4);
            const float4 c = *(const float4*)(p + 32);
            const float4 d = *(const float4*)(p + 36);
            v0[0] = a.x; v0[1] = a.y; v0[2] = a.z; v0[3] = a.w;
            v0[4] = b.x; v0[5] = b.y; v0[6] = b.z; v0[7] = b.w;
            v1[0] = c.x; v1[1] = c.y; v1[2] = c.z; v1[3] = c.w;
            v1[4] = d.x; v1[5] = d.y; v1[6] = d.z; v1[7] = d.w;
        }
        if constexpr (AMODE == 2) {
            const int beg = rowptr[arow], end = rowptr[arow + 1];
            for (int j = beg; j < end; j++) {
                const int s = colidx[j];
                const ushort* np = Ash + (size_t)s * 64 + lk * 8;
                const uint4 n0 = *(const uint4*)np;
                const uint4 n1 = *(const uint4*)(np + 32);
                v0[0] += h2f_lo(n0.x); v0[1] += h2f_hi(n0.x);
                v0[2] += h2f_lo(n0.y); v0[3] += h2f_hi(n0.y);
                v0[4] += h2f_lo(n0.z); v0[5] += h2f_hi(n0.z);
                v0[6] += h2f_lo(n0.w); v0[7] += h2f_hi(n0.w);
                v1[0] += h2f_lo(n1.x); v1[1] += h2f_hi(n1.x);
                v1[2] += h2f_lo(n1.y); v1[3] += h2f_hi(n1.y);
                v1[4] += h2f_lo(n1.z); v1[5] += h2f_hi(n1.z);
                v1[6] += h2f_lo(n1.w); v1[7] += h2f_hi(n1.w);
            }
        }
        U4S8 rh0, rl0, rh1, rl1;
        uint* ph0 = (uint*)&rh0.u; uint* pl0 = (uint*)&rl0.u;
        uint* ph1 = (uint*)&rh1.u; uint* pl1 = (uint*)&rl1.u;
        #pragma unroll
        for (int i = 0; i < 4; i++) {
            split2(v0[2 * i], v0[2 * i + 1], ph0[i], pl0[i]);
            split2(v1[2 * i], v1[2 * i + 1], ph1[i], pl1[i]);
        }
        aHi[0] = rh0.s; aLo[0] = rl0.s;
        aHi[1] = rh1.s; aLo[1] = rl1.s;
    } else {
        U4S8 z; z.u = make_uint4(0, 0, 0, 0);
        aHi[0] = aHi[1] = z.s;
        aLo[0] = aLo[1] = z.s;
    }

    // B fragments: col = nt*16+lr, k = c*32 + lk*8 (contiguous in WT)
    short8 bHi[4][2], bLo[4][2];
    #pragma unroll
    for (int nt = 0; nt < 4; nt++)
        #pragma unroll
        for (int c = 0; c < 2; c++) {
            const int off = (nt * 16 + lr) * 64 + c * 32 + lk * 8;
            U4S8 uh, ul;
            uh.u = *(const uint4*)(WThi + off);
            ul.u = *(const uint4*)(WTlo + off);
            bHi[nt][c] = uh.s;
            bLo[nt][c] = ul.s;
        }

    f32x4 acc[4] = {};
    #pragma unroll
    for (int nt = 0; nt < 4; nt++)
        #pragma unroll
        for (int c = 0; c < 2; c++) {
            acc[nt] = __builtin_amdgcn_mfma_f32_16x16x32_bf16(
                aLo[c], bHi[nt][c], acc[nt], 0, 0, 0);
            acc[nt] = __builtin_amdgcn_mfma_f32_16x16x32_bf16(
                aHi[c], bLo[nt][c], acc[nt], 0, 0, 0);
            acc[nt] = __builtin_amdgcn_mfma_f32_16x16x32_bf16(
                aHi[c], bHi[nt][c], acc[nt], 0, 0, 0);
        }

    // deferred-BN shift coefficients (1+deg) per output row
    float dgf[4] = {};
    if constexpr (AMODE == 2) {
        #pragma unroll
        for (int j = 0; j < 4; j++) {
            const int crow = blockIdx.x * 64 + w * 16 + lk * 4 + j;
            if (crow < Nn) dgf[j] = 1.f + (float)deg[crow];
        }
    }

    // Epilogue: C/D layout col=lane&15, row=(lane>>4)*4+reg  [m89]
    float s[4], s2[4];
    #pragma unroll
    for (int nt = 0; nt < 4; nt++) {
        const int ccol = nt * 16 + lr;
        float bb = bias[ccol];
        float sw = 0.f;
        if constexpr (AMODE == 2) sw = shiftW1[ccol];
        s[nt] = 0.f; s2[nt] = 0.f;
        #pragma unroll
        for (int j = 0; j < 4; j++) {
            const int crow = blockIdx.x * 64 + w * 16 + lk * 4 + j;
            if (crow < Nn) {
                float v = acc[nt][j] + bb;
                if constexpr (AMODE == 2) v = fmaf(dgf[j], sw, v);
                if constexpr (RELU) v = fmaxf(v, 0.f);
                Y[(size_t)crow * 64 + ccol] = v;
                if constexpr (SHADOW) Ys[(size_t)crow * 64 + ccol] = f2h(v);
                if constexpr (STATS) { s[nt] += v; s2[nt] += v * v; }
            }
        }
    }

    if constexpr (STATS) {
        #pragma unroll
        for (int nt = 0; nt < 4; nt++) {
            s[nt]  += __shfl_xor(s[nt], 16);  s[nt]  += __shfl_xor(s[nt], 32);
            s2[nt] += __shfl_xor(s2[nt], 16); s2[nt] += __shfl_xor(s2[nt], 32);
        }
        __shared__ float red[2][4][4][16]; // [s|s2][wave][nt][col16]
        if (l < 16) {
            #pragma unroll
            for (int nt = 0; nt < 4; nt++) {
                red[0][w][nt][l] = s[nt];
                red[1][w][nt][l] = s2[nt];
            }
        }
        __syncthreads();
        if (t < 64) { // column = (t>>4)*16 + (t&15) = t
            float ts = 0.f, ts2 = 0.f;
            #pragma unroll
            for (int wv = 0; wv < 4; wv++) {
                ts  += red[0][wv][t >> 4][t & 15];
                ts2 += red[1][wv][t >> 4][t & 15];
            }
            atomicAdd(&stats[t], ts);
            atomicAdd(&stats[64 + t], ts2);
        }
    }
}

// ---------------------------------------------------------------------------
// CSR build: degree count -> device-wide scan (3 phases) -> scatter-fill
// ---------------------------------------------------------------------------
__global__ __launch_bounds__(256) void count_deg(
    const int* __restrict__ ei, int* __restrict__ deg)
{
    const int e = blockIdx.x * 256 + threadIdx.x;
    if (e < Ee) atomicAdd(&deg[ei[Ee + e]], 1); // dst
}

constexpr int SCAN_TILE = 1024;
constexpr int SCAN_NBLK = (Nn + SCAN_TILE - 1) / SCAN_TILE; // 98

__global__ __launch_bounds__(256) void deg_block_reduce(
    const int* __restrict__ deg, int* __restrict__ blockSums)
{
    const int t = threadIdx.x;
    const int base = blockIdx.x * SCAN_TILE + t * 4;
    int s = 0;
    if (base + 4 <= Nn) {
        const int4 v = *(const int4*)(deg + base);
        s = v.x + v.y + v.z + v.w;
    } else {
        for (int i = 0; i < 4; i++) if (base + i < Nn) s += deg[base + i];
    }
    __shared__ int sh[256];
    sh[t] = s;
    __syncthreads();
    for (int off = 128; off > 0; off >>= 1) {
        if (t < off) sh[t] += sh[t + off];
        __syncthreads();
    }
    if (t == 0) blockSums[blockIdx.x] = sh[0];
}

__global__ __launch_bounds__(128) void scan_blocksums(int* __restrict__ blockSums)
{
    __shared__ int sh[128];
    const int t = threadIdx.x;
    const int v = (t < SCAN_NBLK) ? blockSums[t] : 0;
    sh[t] = v;
    __syncthreads();
    for (int off = 1; off < 128; off <<= 1) {
        const int u = (t >= off) ? sh[t - off] : 0;
        __syncthreads();
        sh[t] += u;
        __syncthreads();
    }
    if (t < SCAN_NBLK) blockSums[t] = sh[t] - v; // exclusive
}

__global__ __launch_bounds__(256) void deg_scan_scatter(
    const int* __restrict__ deg, const int* __restrict__ blockSums,
    int* __restrict__ rowptr, int* __restrict__ cursor)
{
    const int t = threadIdx.x;
    const int base = blockIdx.x * SCAN_TILE + t * 4;
    int v[4];
    int s = 0;
    #pragma unroll
    for (int i = 0; i < 4; i++) {
        const int idx = base + i;
        v[i] = (idx < Nn) ? deg[idx] : 0;
        s += v[i];
    }
    __shared__ int sh[256];
    sh[t] = s;
    __syncthreads();
    for (int off = 1; off < 256; off <<= 1) {
        const int u = (t >= off) ? sh[t - off] : 0;
        __syncthreads();
        sh[t] += u;
        __syncthreads();
    }
    int excl = sh[t] - s + blockSums[blockIdx.x];
    #pragma unroll
    for (int i = 0; i < 4; i++) {
        const int idx = base + i;
        if (idx < Nn) {
            rowptr[idx] = excl;
            cursor[idx] = excl;
            excl += v[i];
        }
    }
    if (blockIdx.x == 0 && t == 0) rowptr[Nn] = Ee;
}

__global__ __launch_bounds__(256) void scatter_fill(
    const int* __restrict__ ei, int* __restrict__ cursor, int* __restrict__ col)
{
    const int e = blockIdx.x * 256 + threadIdx.x;
    if (e >= Ee) return;
    const int s = ei[e];
    const int d = ei[Ee + e];
    const int pos = atomicAdd(&cursor[d], 1);
    col[pos] = s;
}

// ---------------------------------------------------------------------------
// Per-graph column sums of z (f32). 8 blocks per graph; batch sorted.
// ---------------------------------------------------------------------------
__global__ __launch_bounds__(256) void pool_z(
    const float* __restrict__ z, const int* __restrict__ batch,
    float* __restrict__ poolZ)
{
    const int g = blockIdx.x >> 3;
    const int sub = blockIdx.x & 7;
    const int lo = lower_bound_i(batch, Nn, g);
    const int hi = lower_bound_i(batch, Nn, g + 1);
    const int t = threadIdx.x;
    const int cq = t & 15;                 // cols cq*4 .. +3
    const int rg = (t >> 4) + sub * 16;    // 0..127
    float acc[4] = {};
    for (int row = lo + rg; row < hi; row += 128) {
        const float4 v = *(const float4*)(z + (size_t)row * 64 + cq * 4);
        acc[0] += v.x; acc[1] += v.y; acc[2] += v.z; acc[3] += v.w;
    }
    __shared__ float red[16][16][4];
    #pragma unroll
    for (int i = 0; i < 4; i++) red[t >> 4][cq][i] = acc[i];
    __syncthreads();
    if (t < 64) {
        const int c2 = t >> 2, j = t & 3;
        float s = 0.f;
        #pragma unroll
        for (int r = 0; r < 16; r++) s += red[r][c2][j];
        atomicAdd(&poolZ[g * 64 + c2 * 4 + j], s);
    }
}

// Compute scale/shift from stats, then zero stats for the next layer.
__global__ void bn_finalize(
    float* __restrict__ stats, const float* __restrict__ gamma,
    const float* __restrict__ beta, float* __restrict__ sc, int layer)
{
    const int c = threadIdx.x; // 64 threads, 1 block
    const float mean = stats[c] * (1.0f / Nn);
    const float var = stats[64 + c] * (1.0f / Nn) - mean * mean;
    const float scale = gamma[layer * 64 + c] * rsqrtf(var + 1e-5f);
    sc[c] = scale;
    sc[64 + c] = beta[layer * 64 + c] - mean * scale;
    stats[c] = 0.f;
    stats[64 + c] = 0.f;
}

// ---------------------------------------------------------------------------
// Proj head GEMM: (128,320)@(320,320)+b (f32, small).
// ---------------------------------------------------------------------------
template<bool RELU>
__global__ __launch_bounds__(256) void proj(
    const float* __restrict__ X, const float* __restrict__ W,
    const float* __restrict__ bias, float* __restrict__ Y)
{
    const int idx = blockIdx.x * 256 + threadIdx.x; // 40960 exact
    const int r = idx / PDim;
    const int c = idx - r * PDim;
    float acc = bias[c];
    #pragma unroll 8
    for (int k = 0; k < PDim; k++)
        acc = fmaf(X[r * PDim + k], W[k * PDim + c], acc);
    if constexpr (RELU) acc = fmaxf(acc, 0.f);
    Y[idx] = acc;
}

// ---------------------------------------------------------------------------
// Row-wise l2 normalize.
// ---------------------------------------------------------------------------
__global__ __launch_bounds__(64) void l2norm_rows(
    const float* __restrict__ X, float* __restrict__ out)
{
    const int r = blockIdx.x;
    const int l = threadIdx.x;
    float v[5];
    float s = 0.f;
    #pragma unroll
    for (int i = 0; i < 5; i++) {
        v[i] = X[r * PDim + i * 64 + l];
        s += v[i] * v[i];
    }
    #pragma unroll
    for (int off = 32; off > 0; off >>= 1) s += __shfl_down(s, off);
    s = __shfl(s, 0);
    const float d = fmaxf(sqrtf(s), 1e-12f);
    #pragma unroll
    for (int i = 0; i < 5; i++)
        out[r * PDim + i * 64 + l] = v[i] / d;
}

// ---------------------------------------------------------------------------
extern "C" void kernel_launch(void* const* d_in, const int* in_sizes, int n_in,
                              void* d_out, int out_size, void* d_ws, size_t ws_size,
                              hipStream_t stream)
{
    const float* x     = (const float*)d_in[0];
    const int*   ei    = (const int*)d_in[1];
    const int*   batch = (const int*)d_in[2];
    const float* Ws    = (const float*)d_in[3];
    const float* bs    = (const float*)d_in[4];
    const float* W1    = (const float*)d_in[5];
    const float* b1    = (const float*)d_in[6];
    const float* W2    = (const float*)d_in[7];
    const float* b2    = (const float*)d_in[8];
    const float* gamma = (const float*)d_in[9];
    const float* beta  = (const float*)d_in[10];
    const float* Wp1   = (const float*)d_in[11];
    const float* bp1   = (const float*)d_in[12];
    const float* Wp2   = (const float*)d_in[13];
    const float* bp2   = (const float*)d_in[14];
    float* out = (float*)d_out;

    // workspace (all segments 16B-aligned by construction)
    float*  Zf  = (float*)d_ws;                   // z  f32 (N*64)     25.6MB
    float*  Mf  = Zf + (size_t)Nn * 64;           // MLP hidden f32    25.6MB
    ushort* Zs  = (ushort*)(Mf + (size_t)Nn * 64);// z fp16 shadow     12.8MB
    ushort* WThi = Zs + (size_t)Nn * 64;          // 6*4096 (Ws + W2s)
    ushort* WTlo = WThi + 6 * 4096;
    ushort* WT1hi = WTlo + 6 * 4096;              // per-layer scaled W1
    ushort* WT1lo = WT1hi + 4096;
    float* pooled = (float*)(WT1lo + 4096);       // (G,320)
    float* ytmp   = pooled + (size_t)Gg * PDim;
    float* ypro   = ytmp + (size_t)Gg * PDim;
    float* stats  = ypro + (size_t)Gg * PDim;     // 128
    float* sc     = stats + 128;                  // 128
    float* shiftW1 = sc + 128;                    // 64
    float* poolZ  = shiftW1 + 64;                 // G*64
    int* cnt    = (int*)(poolZ + Gg * 64);        // G
    int* deg    = cnt + Gg;                       // N
    int* rowptr = deg + Nn;                       // N+1
    int* cursor = rowptr + Nn + 1;                // N
    int* colidx = cursor + Nn;                    // E
    int* bsums  = colidx + Ee;                    // 98

    const int gemmGrid = (Nn + 63) / 64;          // 1563
    const int edgeGrid = (Ee + 255) / 256;

    hipMemsetAsync(deg, 0, Nn * sizeof(int), stream);
    init_misc<<<1, 256, 0, stream>>>(batch, sc, stats, poolZ, cnt);
    conv_weights<<<6, 256, 0, stream>>>(Ws, W2, WThi, WTlo);

    // CSR build
    count_deg<<<edgeGrid, 256, 0, stream>>>(ei, deg);
    deg_block_reduce<<<SCAN_NBLK, 256, 0, stream>>>(deg, bsums);
    scan_blocksums<<<1, 128, 0, stream>>>(bsums);
    deg_scan_scatter<<<SCAN_NBLK, 256, 0, stream>>>(deg, bsums, rowptr, cursor);
    scatter_fill<<<edgeGrid, 256, 0, stream>>>(ei, cursor, colidx);

    // encoder: Zf = x @ Ws + bs (f32), Zs = fp16 shadow ("z_{-1}", identity BN)
    gemm_mfma<0, false, false, true><<<gemmGrid, 256, 0, stream>>>(
        x, nullptr, nullptr, nullptr, nullptr, nullptr,
        WThi, WTlo, bs, Zf, Zs, nullptr);

    for (int l = 0; l < Ll; l++) {
        // fold scale into W1, compute shiftW1, finalize pooled[l-1], zero poolZ
        prep_layer<<<49, 256, 0, stream>>>(
            W1 + (size_t)l * 4096, sc, WT1hi, WT1lo, shiftW1, poolZ, cnt,
            pooled, l);
        // Mf = relu( (z_self + agg(z)) @ W1' + b1 + (1+deg)*shiftW1 )
        gemm_mfma<2, true, false, false><<<gemmGrid, 256, 0, stream>>>(
            Zf, Zs, rowptr, colidx, deg, shiftW1,
            WT1hi, WT1lo, b1 + (size_t)l * 64, Mf, nullptr, nullptr);
        // z = relu(Mf @ W2 + b2) -> Zf/Zs, fused BN stats
        gemm_mfma<0, true, true, true><<<gemmGrid, 256, 0, stream>>>(
            Mf, nullptr, nullptr, nullptr, nullptr, nullptr,
            WThi + (size_t)(1 + l) * 4096, WTlo + (size_t)(1 + l) * 4096,
            b2 + (size_t)l * 64, Zf, Zs, stats);
        bn_finalize<<<1, 64, 0, stream>>>(stats, gamma, beta, sc, l);
        pool_z<<<Gg * 8, 256, 0, stream>>>(Zf, batch, poolZ);
    }
    final_pool<<<32, 256, 0, stream>>>(sc, poolZ, cnt, pooled);

    // proj head (f32)
    proj<true><<<160, 256, 0, stream>>>(pooled, Wp1, bp1, ytmp);
    proj<false><<<160, 256, 0, stream>>>(ytmp, Wp2, bp2, ypro);

    l2norm_rows<<<Gg, 64, 0, stream>>>(ypro, out);               // out0
    l2norm_rows<<<Gg, 64, 0, stream>>>(pooled, out + Gg * PDim); // out1
}